// Round 5
// baseline (412.474 us; speedup 1.0000x reference)
//
#include <hip/hip_runtime.h>
#include <hip/hip_bf16.h>
#include <math.h>

#define D_MODEL 768
#define N_HEADS 12
#define D_HEAD  64
#define BATCH   2
#define SEQ     2048
#define ROWS    (BATCH*SEQ)          // 4096
#define D_FFN   (4*D_MODEL)          // 3072

typedef short bf16x8 __attribute__((ext_vector_type(8)));
typedef float f32x4  __attribute__((ext_vector_type(4)));

__device__ __forceinline__ short f2bf(float f) {
    __hip_bfloat16 h = __float2bfloat16(f);
    return *reinterpret_cast<short*>(&h);
}

// ---------------------------------------------------------------- converts
__global__ __launch_bounds__(256)
void convert_bf16_kernel(const float* __restrict__ in, short* __restrict__ out) {
    int i = (blockIdx.x * 256 + threadIdx.x) * 8;
    float4 a = *reinterpret_cast<const float4*>(in + i);
    float4 b = *reinterpret_cast<const float4*>(in + i + 4);
    bf16x8 r;
    r[0]=f2bf(a.x); r[1]=f2bf(a.y); r[2]=f2bf(a.z); r[3]=f2bf(a.w);
    r[4]=f2bf(b.x); r[5]=f2bf(b.y); r[6]=f2bf(b.z); r[7]=f2bf(b.w);
    *reinterpret_cast<bf16x8*>(out + i) = r;
}

// W[K][N] fp32 -> WT[N][K] bf16 (tiled transpose)
__global__ __launch_bounds__(256)
void transpose_bf16_kernel(const float* __restrict__ W, short* __restrict__ WT,
                           int K, int N) {
    __shared__ float tile[32][33];
    int n0 = blockIdx.x * 32, k0 = blockIdx.y * 32;
    int tx = threadIdx.x & 31, ty = threadIdx.x >> 5;   // 32 x 8
    #pragma unroll
    for (int i = 0; i < 4; ++i)
        tile[ty + 8*i][tx] = W[(size_t)(k0 + ty + 8*i) * N + n0 + tx];
    __syncthreads();
    #pragma unroll
    for (int i = 0; i < 4; ++i)
        WT[(size_t)(n0 + ty + 8*i) * K + k0 + tx] = f2bf(tile[tx][ty + 8*i]);
}

// Vm [ROWS][768] bf16 -> Vt [24][64][2048] bf16 (per-head V^T)
__global__ __launch_bounds__(256)
void transpose_v_kernel(const short* __restrict__ Vm, short* __restrict__ Vt) {
    __shared__ short tile[64][72];
    int kt = blockIdx.x;        // 32 k-tiles of 64
    int bh = blockIdx.y;        // 24
    int b = bh / N_HEADS, h = bh % N_HEADS;
    int tid = threadIdx.x;
    int row = tid >> 2, c16 = (tid & 3) * 16;
    const short* src = Vm + ((size_t)(b * SEQ) + kt * 64 + row) * D_MODEL + h * 64 + c16;
    *reinterpret_cast<bf16x8*>(&tile[row][c16])     = *reinterpret_cast<const bf16x8*>(src);
    *reinterpret_cast<bf16x8*>(&tile[row][c16 + 8]) = *reinterpret_cast<const bf16x8*>(src + 8);
    __syncthreads();
    int d = tid >> 2, k16 = (tid & 3) * 16;
    short o[16];
    #pragma unroll
    for (int j = 0; j < 16; ++j) o[j] = tile[k16 + j][d];
    short* dst = Vt + ((size_t)bh * 64 + d) * SEQ + kt * 64 + k16;
    *reinterpret_cast<bf16x8*>(dst)     = *reinterpret_cast<bf16x8*>(&o[0]);
    *reinterpret_cast<bf16x8*>(dst + 8) = *reinterpret_cast<bf16x8*>(&o[8]);
}

// ---------------------------------------------------------------- LayerNorm (fp32 in -> bf16 out)
__global__ __launch_bounds__(256)
void ln_kernel(const float* __restrict__ x, const float* __restrict__ g,
               const float* __restrict__ beta, short* __restrict__ out) {
    int row = blockIdx.x;
    const float* xr = x + (size_t)row * D_MODEL;
    int t = threadIdx.x;
    float v0 = xr[t], v1 = xr[t + 256], v2 = xr[t + 512];
    float s  = v0 + v1 + v2;
    float s2 = v0*v0 + v1*v1 + v2*v2;
    __shared__ float rs[4], rs2[4];
    #pragma unroll
    for (int off = 32; off; off >>= 1) {
        s  += __shfl_down(s, off);
        s2 += __shfl_down(s2, off);
    }
    int wv = t >> 6, ln = t & 63;
    if (ln == 0) { rs[wv] = s; rs2[wv] = s2; }
    __syncthreads();
    float S  = rs[0] + rs[1] + rs[2] + rs[3];
    float S2 = rs2[0] + rs2[1] + rs2[2] + rs2[3];
    float mu  = S * (1.0f / D_MODEL);
    float var = S2 * (1.0f / D_MODEL) - mu * mu;
    float inv = rsqrtf(var + 1e-5f);
    short* orow = out + (size_t)row * D_MODEL;
    orow[t]       = f2bf((v0 - mu) * inv * g[t]       + beta[t]);
    orow[t + 256] = f2bf((v1 - mu) * inv * g[t + 256] + beta[t + 256]);
    orow[t + 512] = f2bf((v2 - mu) * inv * g[t + 512] + beta[t + 512]);
}

// ---------------------------------------------------------------- bf16 MFMA GEMM (m97 structure)
template<int ACT, bool RES, bool OUTBF>
__device__ __forceinline__
void gemm_body(const short* __restrict__ A, const short* __restrict__ WT,
               const float* __restrict__ bias, const float* __restrict__ res,
               void* __restrict__ Cout, int M, int N, int K) {
    __shared__ short As[128 * 32];
    __shared__ short Bs[128 * 32];
    const int tid = threadIdx.x;
    const int w = tid >> 6, lane = tid & 63;
    const int lr = lane & 15, lg = lane >> 4;
    const int wm = w >> 1, wn = w & 1;
    const int bm = blockIdx.y * 128, bn = blockIdx.x * 128;

    f32x4 acc[4][4] = {};

    const int srow = w * 32 + (lane >> 2);
    const int scol = (lane & 3) * 8;
    const short* Ag = A  + (size_t)(bm + srow) * K + scol;
    const short* Bg = WT + (size_t)(bn + srow) * K + scol;

    for (int k0 = 0; k0 < K; k0 += 32) {
        __syncthreads();
        #pragma unroll
        for (int r = 0; r < 2; ++r) {
            __builtin_amdgcn_global_load_lds(
                (const __attribute__((address_space(1))) void*)(Ag + (size_t)r * 16 * K + k0),
                (__attribute__((address_space(3))) void*)(As + w * 1024 + r * 512),
                16, 0, 0);
            __builtin_amdgcn_global_load_lds(
                (const __attribute__((address_space(1))) void*)(Bg + (size_t)r * 16 * K + k0),
                (__attribute__((address_space(3))) void*)(Bs + w * 1024 + r * 512),
                16, 0, 0);
        }
        __syncthreads();
        bf16x8 af[4], bfr[4];
        #pragma unroll
        for (int mi = 0; mi < 4; ++mi)
            af[mi] = *reinterpret_cast<const bf16x8*>(As + (wm*64 + mi*16 + lr) * 32 + lg*8);
        #pragma unroll
        for (int nj = 0; nj < 4; ++nj)
            bfr[nj] = *reinterpret_cast<const bf16x8*>(Bs + (wn*64 + nj*16 + lr) * 32 + lg*8);
        #pragma unroll
        for (int mi = 0; mi < 4; ++mi)
            #pragma unroll
            for (int nj = 0; nj < 4; ++nj)
                acc[mi][nj] = __builtin_amdgcn_mfma_f32_16x16x32_bf16(af[mi], bfr[nj], acc[mi][nj], 0, 0, 0);
    }

    float bias_v[4];
    #pragma unroll
    for (int nj = 0; nj < 4; ++nj) bias_v[nj] = bias[bn + wn*64 + nj*16 + lr];

    #pragma unroll
    for (int mi = 0; mi < 4; ++mi) {
        #pragma unroll
        for (int j = 0; j < 4; ++j) {
            size_t m = bm + wm*64 + mi*16 + lg*4 + j;
            #pragma unroll
            for (int nj = 0; nj < 4; ++nj) {
                size_t n = bn + wn*64 + nj*16 + lr;
                float v = acc[mi][nj][j] + bias_v[nj];
                if (RES) v += res[m * N + n];
                if (ACT == 1) v = 0.5f * v * (1.0f + erff(v * 0.70710678118f));
                if (OUTBF) ((short*)Cout)[m * N + n] = f2bf(v);
                else       ((float*)Cout)[m * N + n] = v;
            }
        }
    }
}

template<int ACT, bool RES, bool OUTBF>
__global__ __launch_bounds__(256)
void gemm_mfma_kernel(const short* __restrict__ A, const short* __restrict__ WT,
                      const float* __restrict__ bias, const float* __restrict__ res,
                      void* __restrict__ Cout, int M, int N, int K) {
    gemm_body<ACT, RES, OUTBF>(A, WT, bias, res, Cout, M, N, K);
}

__global__ __launch_bounds__(256)
void gemm_qkv_kernel(const short* __restrict__ A,
                     const short* __restrict__ WTq, const short* __restrict__ WTk,
                     const short* __restrict__ WTv,
                     const float* __restrict__ bq, const float* __restrict__ bk,
                     const float* __restrict__ bv,
                     short* __restrict__ Qm, short* __restrict__ Km, short* __restrict__ Vm) {
    const short* WT; const float* bias; short* C;
    if (blockIdx.z == 0)      { WT = WTq; bias = bq; C = Qm; }
    else if (blockIdx.z == 1) { WT = WTk; bias = bk; C = Km; }
    else                      { WT = WTv; bias = bv; C = Vm; }
    gemm_body<0, false, true>(A, WT, bias, nullptr, C, ROWS, D_MODEL, D_MODEL);
}

// ---------------------------------------------------------------- MFMA flash attention v4
// 1 wave per block. Wave task = (bh, pair, half): processes 16-row q-tiles
// pair and 127-pair; for each, k-tiles half, half+2,... (2-way K split).
// Writes fp32 partials (m,l,o); merge kernel combines the two halves.
__global__ __launch_bounds__(64, 3)
void attn_mfma_kernel(const short* __restrict__ Q, const short* __restrict__ K,
                      const short* __restrict__ Vt, const short* __restrict__ qp,
                      const short* __restrict__ kp,
                      float* __restrict__ o_part, float* __restrict__ ml_part) {
    int lin = blockIdx.x;                     // 0..3071
    int wid = (lin & 7) * 384 + (lin >> 3);   // bijective XCD swizzle (3072=8*384)
    int half = wid & 1;
    int pair = (wid >> 1) & 63;
    int bh   = wid >> 7;                      // 0..23
    int b = bh / N_HEADS, h = bh % N_HEADS;
    __shared__ short Plds[16][72];
    int lane = threadIdx.x;
    int lr = lane & 15, lg = lane >> 4;

    const short* Kh  = K  + (size_t)(b * SEQ) * D_MODEL + h * 64;
    const short* kph = kp + (size_t)bh * SEQ * 64;
    const short* Vth = Vt + (size_t)bh * 64 * SEQ;

    #pragma unroll
    for (int phase = 0; phase < 2; ++phase) {
        int qt = phase ? 127 - pair : pair;   // 16-row q-tile 0..127
        int qbase = qt * 16;

        const short* Qrow  = Q  + ((size_t)(b * SEQ) + qbase + lr) * D_MODEL + h * 64;
        const short* qprow = qp + ((size_t)bh * SEQ + qbase + lr) * 64;
        bf16x8 qf0  = *reinterpret_cast<const bf16x8*>(Qrow + lg * 8);
        bf16x8 qf1  = *reinterpret_cast<const bf16x8*>(Qrow + 32 + lg * 8);
        bf16x8 qpf0 = *reinterpret_cast<const bf16x8*>(qprow + lg * 8);
        bf16x8 qpf1 = *reinterpret_cast<const bf16x8*>(qprow + 32 + lg * 8);

        f32x4 o_acc[4] = {};
        float m_run[4], l_run[4];
        #pragma unroll
        for (int r = 0; r < 4; ++r) { m_run[r] = -1e30f; l_run[r] = 0.f; }

        int nkt = qt / 4 + 1;
        int lastkt = nkt - 1;

        bf16x8 kf[4][2], kq[4][2];
        if (half < nkt) {
            #pragma unroll
            for (int sub = 0; sub < 4; ++sub) {
                const short* kr  = Kh  + (size_t)(half * 64 + sub * 16 + lr) * D_MODEL;
                const short* kpr = kph + (size_t)(half * 64 + sub * 16 + lr) * 64;
                kf[sub][0] = *reinterpret_cast<const bf16x8*>(kr + lg * 8);
                kf[sub][1] = *reinterpret_cast<const bf16x8*>(kr + 32 + lg * 8);
                kq[sub][0] = *reinterpret_cast<const bf16x8*>(kpr + lg * 8);
                kq[sub][1] = *reinterpret_cast<const bf16x8*>(kpr + 32 + lg * 8);
            }
        }

        for (int kt = half; kt < nkt; kt += 2) {
            bf16x8 vb[4][2];
            #pragma unroll
            for (int ds = 0; ds < 4; ++ds) {
                const short* vr = Vth + (size_t)(ds * 16 + lr) * SEQ + kt * 64;
                vb[ds][0] = *reinterpret_cast<const bf16x8*>(vr + lg * 8);
                vb[ds][1] = *reinterpret_cast<const bf16x8*>(vr + 32 + lg * 8);
            }

            f32x4 sx[4] = {}, sp[4] = {};
            __builtin_amdgcn_s_setprio(1);
            #pragma unroll
            for (int sub = 0; sub < 4; ++sub) {
                sx[sub] = __builtin_amdgcn_mfma_f32_16x16x32_bf16(qf0,  kf[sub][0], sx[sub], 0, 0, 0);
                sx[sub] = __builtin_amdgcn_mfma_f32_16x16x32_bf16(qf1,  kf[sub][1], sx[sub], 0, 0, 0);
                sp[sub] = __builtin_amdgcn_mfma_f32_16x16x32_bf16(qpf0, kq[sub][0], sp[sub], 0, 0, 0);
                sp[sub] = __builtin_amdgcn_mfma_f32_16x16x32_bf16(qpf1, kq[sub][1], sp[sub], 0, 0, 0);
            }
            __builtin_amdgcn_s_setprio(0);

            if (kt + 2 < nkt) {
                #pragma unroll
                for (int sub = 0; sub < 4; ++sub) {
                    const short* kr  = Kh  + (size_t)((kt + 2) * 64 + sub * 16 + lr) * D_MODEL;
                    const short* kpr = kph + (size_t)((kt + 2) * 64 + sub * 16 + lr) * 64;
                    kf[sub][0] = *reinterpret_cast<const bf16x8*>(kr + lg * 8);
                    kf[sub][1] = *reinterpret_cast<const bf16x8*>(kr + 32 + lg * 8);
                    kq[sub][0] = *reinterpret_cast<const bf16x8*>(kpr + lg * 8);
                    kq[sub][1] = *reinterpret_cast<const bf16x8*>(kpr + 32 + lg * 8);
                }
            }

            float sc[4][4];
            float pmax[4];
            bool diag = (kt == lastkt);
            #pragma unroll
            for (int r = 0; r < 4; ++r) {
                int row = qbase + lg * 4 + r;
                float mx = -1e30f;
                #pragma unroll
                for (int sub = 0; sub < 4; ++sub) {
                    float v = sx[sub][r] * sp[sub][r] * (1.0f / 64.0f);
                    if (diag) {
                        int col = kt * 64 + sub * 16 + lr;
                        if (col > row) v = -1e30f;
                    }
                    sc[sub][r] = v;
                    mx = fmaxf(mx, v);
                }
                pmax[r] = mx;
            }
            #pragma unroll
            for (int off = 1; off < 16; off <<= 1)
                #pragma unroll
                for (int r = 0; r < 4; ++r)
                    pmax[r] = fmaxf(pmax[r], __shfl_xor(pmax[r], off));

            float psum[4];
            #pragma unroll
            for (int r = 0; r < 4; ++r) {
                float m_new = fmaxf(m_run[r], pmax[r]);
                float scale = __expf(m_run[r] - m_new);
                m_run[r] = m_new;
                float s = 0.f;
                #pragma unroll
                for (int sub = 0; sub < 4; ++sub) {
                    float p = __expf(sc[sub][r] - m_new);
                    sc[sub][r] = p;
                    s += p;
                }
                psum[r] = s;
                l_run[r] *= scale;
                #pragma unroll
                for (int ds = 0; ds < 4; ++ds) o_acc[ds][r] *= scale;
            }
            #pragma unroll
            for (int off = 1; off < 16; off <<= 1)
                #pragma unroll
                for (int r = 0; r < 4; ++r)
                    psum[r] += __shfl_xor(psum[r], off);
            #pragma unroll
            for (int r = 0; r < 4; ++r) l_run[r] += psum[r];

            #pragma unroll
            for (int sub = 0; sub < 4; ++sub)
                #pragma unroll
                for (int r = 0; r < 4; ++r)
                    Plds[lg * 4 + r][sub * 16 + lr] = f2bf(sc[sub][r]);

            bf16x8 pa0 = *reinterpret_cast<bf16x8*>(&Plds[lr][lg * 8]);
            bf16x8 pa1 = *reinterpret_cast<bf16x8*>(&Plds[lr][32 + lg * 8]);

            __builtin_amdgcn_s_setprio(1);
            #pragma unroll
            for (int ds = 0; ds < 4; ++ds) {
                o_acc[ds] = __builtin_amdgcn_mfma_f32_16x16x32_bf16(pa0, vb[ds][0], o_acc[ds], 0, 0, 0);
                o_acc[ds] = __builtin_amdgcn_mfma_f32_16x16x32_bf16(pa1, vb[ds][1], o_acc[ds], 0, 0, 0);
            }
            __builtin_amdgcn_s_setprio(0);
        }

        // write partials
        size_t idx = ((size_t)bh * 128 + qt) * 2 + half;
        float* op = o_part + idx * 1024;
        #pragma unroll
        for (int ds = 0; ds < 4; ++ds)
            #pragma unroll
            for (int r = 0; r < 4; ++r)
                op[(lg * 4 + r) * 64 + ds * 16 + lr] = o_acc[ds][r];
        if (lr == 0) {
            #pragma unroll
            for (int r = 0; r < 4; ++r) {
                ml_part[idx * 32 + lg * 4 + r]      = m_run[r];
                ml_part[idx * 32 + 16 + lg * 4 + r] = l_run[r];
            }
        }
    }
}

// merge the two K-halves -> ao (bf16)
__global__ __launch_bounds__(64)
void attn_merge_kernel(const float* __restrict__ o_part, const float* __restrict__ ml_part,
                       short* __restrict__ ao) {
    int blk = blockIdx.x;            // bh*128 + qt
    int bh = blk >> 7, qt = blk & 127;
    int b = bh / N_HEADS, h = bh % N_HEADS;
    int d = threadIdx.x;
    size_t i0 = (size_t)blk * 2, i1 = i0 + 1;
    const float* O0 = o_part + i0 * 1024;
    const float* O1 = o_part + i1 * 1024;
    const float* M0 = ml_part + i0 * 32;
    const float* M1 = ml_part + i1 * 32;
    #pragma unroll 4
    for (int r = 0; r < 16; ++r) {
        float m0 = M0[r], l0 = M0[16 + r];
        float m1 = M1[r], l1 = M1[16 + r];
        float mm = fmaxf(m0, m1);
        float e0 = __expf(m0 - mm), e1 = __expf(m1 - mm);
        float l = l0 * e0 + l1 * e1;
        float o = O0[r * 64 + d] * e0 + O1[r * 64 + d] * e1;
        int row = qt * 16 + r;
        ao[((size_t)(b * SEQ) + row) * D_MODEL + h * 64 + d] = f2bf(o / l);
    }
}

// ---------------------------------------------------------------- launch
extern "C" void kernel_launch(void* const* d_in, const int* in_sizes, int n_in,
                              void* d_out, int out_size, void* d_ws, size_t ws_size,
                              hipStream_t stream) {
    const float* x     = (const float*)d_in[0];
    const float* q_pos = (const float*)d_in[1];
    const float* k_pos = (const float*)d_in[2];
    const float* Wq = (const float*)d_in[4];
    const float* bq = (const float*)d_in[5];
    const float* Wk = (const float*)d_in[6];
    const float* bk = (const float*)d_in[7];
    const float* Wv = (const float*)d_in[8];
    const float* bv = (const float*)d_in[9];
    const float* Wo = (const float*)d_in[10];
    const float* bo = (const float*)d_in[11];
    const float* ln1_g = (const float*)d_in[12];
    const float* ln1_b = (const float*)d_in[13];
    const float* ln2_g = (const float*)d_in[14];
    const float* ln2_b = (const float*)d_in[15];
    const float* W1 = (const float*)d_in[16];
    const float* b1 = (const float*)d_in[17];
    const float* W2 = (const float*)d_in[18];
    const float* b2 = (const float*)d_in[19];
    float* out = (float*)d_out;

    char* p = (char*)d_ws;
    auto alloc = [&](size_t bytes) { char* q = p; p += (bytes + 255) & ~(size_t)255; return q; };
    const size_t SA = (size_t)ROWS * D_MODEL;
    const size_t SP = (size_t)BATCH * N_HEADS * SEQ * 64;

    short* h_bf  = (short*)alloc(SA * 2);
    short* Qm    = (short*)alloc(SA * 2);
    short* Km    = (short*)alloc(SA * 2);
    short* Vm    = (short*)alloc(SA * 2);
    short* Vt    = (short*)alloc(SP * 2);
    short* ao    = (short*)alloc(SA * 2);
    short* qp_bf = (short*)alloc(SP * 2);
    short* kp_bf = (short*)alloc(SP * 2);
    short* mid   = (short*)alloc((size_t)ROWS * D_FFN * 2);
    float* x2    = (float*)alloc(SA * 4);
    short* WTq   = (short*)alloc((size_t)D_MODEL * D_MODEL * 2);
    short* WTk   = (short*)alloc((size_t)D_MODEL * D_MODEL * 2);
    short* WTv   = (short*)alloc((size_t)D_MODEL * D_MODEL * 2);
    short* WTo   = (short*)alloc((size_t)D_MODEL * D_MODEL * 2);
    short* WT1   = (short*)alloc((size_t)D_MODEL * D_FFN * 2);
    short* WT2   = (short*)alloc((size_t)D_MODEL * D_FFN * 2);

    // attention partials alias buffers that are dead during attention:
    // o_part (25.2 MB) == mid ; ml_part (0.8 MB) == start of x2
    float* o_part  = (float*)mid;
    float* ml_part = (float*)x2;

    dim3 t768(24, 24), t1(96, 24), t2(24, 96);
    transpose_bf16_kernel<<<t768, 256, 0, stream>>>(Wq, WTq, D_MODEL, D_MODEL);
    transpose_bf16_kernel<<<t768, 256, 0, stream>>>(Wk, WTk, D_MODEL, D_MODEL);
    transpose_bf16_kernel<<<t768, 256, 0, stream>>>(Wv, WTv, D_MODEL, D_MODEL);
    transpose_bf16_kernel<<<t768, 256, 0, stream>>>(Wo, WTo, D_MODEL, D_MODEL);
    transpose_bf16_kernel<<<t1,   256, 0, stream>>>(W1, WT1, D_MODEL, D_FFN);
    transpose_bf16_kernel<<<t2,   256, 0, stream>>>(W2, WT2, D_FFN, D_MODEL);
    convert_bf16_kernel<<<SP / 2048, 256, 0, stream>>>(q_pos, qp_bf);
    convert_bf16_kernel<<<SP / 2048, 256, 0, stream>>>(k_pos, kp_bf);

    ln_kernel<<<ROWS, 256, 0, stream>>>(x, ln1_g, ln1_b, h_bf);
    gemm_qkv_kernel<<<dim3(D_MODEL/128, ROWS/128, 3), 256, 0, stream>>>(
        h_bf, WTq, WTk, WTv, bq, bk, bv, Qm, Km, Vm);
    transpose_v_kernel<<<dim3(SEQ/64, BATCH*N_HEADS), 256, 0, stream>>>(Vm, Vt);
    attn_mfma_kernel<<<3072, 64, 0, stream>>>(Qm, Km, Vt, qp_bf, kp_bf, o_part, ml_part);
    attn_merge_kernel<<<3072, 64, 0, stream>>>(o_part, ml_part, ao);
    gemm_mfma_kernel<0, true, false><<<dim3(D_MODEL/128, ROWS/128), 256, 0, stream>>>(
        ao, WTo, bo, x, x2, ROWS, D_MODEL, D_MODEL);
    ln_kernel<<<ROWS, 256, 0, stream>>>(x2, ln2_g, ln2_b, h_bf);
    gemm_mfma_kernel<1, false, true><<<dim3(D_FFN/128, ROWS/128), 256, 0, stream>>>(
        h_bf, WT1, b1, nullptr, mid, ROWS, D_FFN, D_MODEL);
    gemm_mfma_kernel<0, true, false><<<dim3(D_MODEL/128, ROWS/128), 256, 0, stream>>>(
        mid, WT2, b2, x2, out, ROWS, D_MODEL, D_FFN);
}

// Round 6
// 351.667 us; speedup vs baseline: 1.1729x; 1.1729x over previous
//
#include <hip/hip_runtime.h>
#include <hip/hip_bf16.h>
#include <math.h>

#define D_MODEL 768
#define N_HEADS 12
#define D_HEAD  64
#define BATCH   2
#define SEQ     2048
#define ROWS    (BATCH*SEQ)          // 4096
#define D_FFN   (4*D_MODEL)          // 3072

typedef short bf16x8 __attribute__((ext_vector_type(8)));
typedef float f32x4  __attribute__((ext_vector_type(4)));

__device__ __forceinline__ short f2bf(float f) {
    __hip_bfloat16 h = __float2bfloat16(f);
    return *reinterpret_cast<short*>(&h);
}

// ---------------------------------------------------------------- converts
__global__ __launch_bounds__(256)
void convert_bf16_kernel(const float* __restrict__ in, short* __restrict__ out) {
    int i = (blockIdx.x * 256 + threadIdx.x) * 8;
    float4 a = *reinterpret_cast<const float4*>(in + i);
    float4 b = *reinterpret_cast<const float4*>(in + i + 4);
    bf16x8 r;
    r[0]=f2bf(a.x); r[1]=f2bf(a.y); r[2]=f2bf(a.z); r[3]=f2bf(a.w);
    r[4]=f2bf(b.x); r[5]=f2bf(b.y); r[6]=f2bf(b.z); r[7]=f2bf(b.w);
    *reinterpret_cast<bf16x8*>(out + i) = r;
}

// W[K][N] fp32 -> WT[N][K] bf16 (tiled transpose)
__global__ __launch_bounds__(256)
void transpose_bf16_kernel(const float* __restrict__ W, short* __restrict__ WT,
                           int K, int N) {
    __shared__ float tile[32][33];
    int n0 = blockIdx.x * 32, k0 = blockIdx.y * 32;
    int tx = threadIdx.x & 31, ty = threadIdx.x >> 5;   // 32 x 8
    #pragma unroll
    for (int i = 0; i < 4; ++i)
        tile[ty + 8*i][tx] = W[(size_t)(k0 + ty + 8*i) * N + n0 + tx];
    __syncthreads();
    #pragma unroll
    for (int i = 0; i < 4; ++i)
        WT[(size_t)(n0 + ty + 8*i) * K + k0 + tx] = f2bf(tile[tx][ty + 8*i]);
}

// Vm [ROWS][768] bf16 -> Vt [24][64][2048] bf16 (per-head V^T)
__global__ __launch_bounds__(256)
void transpose_v_kernel(const short* __restrict__ Vm, short* __restrict__ Vt) {
    __shared__ short tile[64][72];
    int kt = blockIdx.x;        // 32 k-tiles of 64
    int bh = blockIdx.y;        // 24
    int b = bh / N_HEADS, h = bh % N_HEADS;
    int tid = threadIdx.x;
    int row = tid >> 2, c16 = (tid & 3) * 16;
    const short* src = Vm + ((size_t)(b * SEQ) + kt * 64 + row) * D_MODEL + h * 64 + c16;
    *reinterpret_cast<bf16x8*>(&tile[row][c16])     = *reinterpret_cast<const bf16x8*>(src);
    *reinterpret_cast<bf16x8*>(&tile[row][c16 + 8]) = *reinterpret_cast<const bf16x8*>(src + 8);
    __syncthreads();
    int d = tid >> 2, k16 = (tid & 3) * 16;
    short o[16];
    #pragma unroll
    for (int j = 0; j < 16; ++j) o[j] = tile[k16 + j][d];
    short* dst = Vt + ((size_t)bh * 64 + d) * SEQ + kt * 64 + k16;
    *reinterpret_cast<bf16x8*>(dst)     = *reinterpret_cast<bf16x8*>(&o[0]);
    *reinterpret_cast<bf16x8*>(dst + 8) = *reinterpret_cast<bf16x8*>(&o[8]);
}

// ---------------------------------------------------------------- LayerNorm (fp32 in -> bf16 out)
__global__ __launch_bounds__(256)
void ln_kernel(const float* __restrict__ x, const float* __restrict__ g,
               const float* __restrict__ beta, short* __restrict__ out) {
    int row = blockIdx.x;
    const float* xr = x + (size_t)row * D_MODEL;
    int t = threadIdx.x;
    float v0 = xr[t], v1 = xr[t + 256], v2 = xr[t + 512];
    float s  = v0 + v1 + v2;
    float s2 = v0*v0 + v1*v1 + v2*v2;
    __shared__ float rs[4], rs2[4];
    #pragma unroll
    for (int off = 32; off; off >>= 1) {
        s  += __shfl_down(s, off);
        s2 += __shfl_down(s2, off);
    }
    int wv = t >> 6, ln = t & 63;
    if (ln == 0) { rs[wv] = s; rs2[wv] = s2; }
    __syncthreads();
    float S  = rs[0] + rs[1] + rs[2] + rs[3];
    float S2 = rs2[0] + rs2[1] + rs2[2] + rs2[3];
    float mu  = S * (1.0f / D_MODEL);
    float var = S2 * (1.0f / D_MODEL) - mu * mu;
    float inv = rsqrtf(var + 1e-5f);
    short* orow = out + (size_t)row * D_MODEL;
    orow[t]       = f2bf((v0 - mu) * inv * g[t]       + beta[t]);
    orow[t + 256] = f2bf((v1 - mu) * inv * g[t + 256] + beta[t + 256]);
    orow[t + 512] = f2bf((v2 - mu) * inv * g[t + 512] + beta[t + 512]);
}

// ---------------------------------------------------------------- bf16 MFMA GEMM (m97 structure)
template<int ACT, bool RES, bool OUTBF>
__device__ __forceinline__
void gemm_body(const short* __restrict__ A, const short* __restrict__ WT,
               const float* __restrict__ bias, const float* __restrict__ res,
               void* __restrict__ Cout, int M, int N, int K) {
    __shared__ short As[128 * 32];
    __shared__ short Bs[128 * 32];
    const int tid = threadIdx.x;
    const int w = tid >> 6, lane = tid & 63;
    const int lr = lane & 15, lg = lane >> 4;
    const int wm = w >> 1, wn = w & 1;
    const int bm = blockIdx.y * 128, bn = blockIdx.x * 128;

    f32x4 acc[4][4] = {};

    const int srow = w * 32 + (lane >> 2);
    const int scol = (lane & 3) * 8;
    const short* Ag = A  + (size_t)(bm + srow) * K + scol;
    const short* Bg = WT + (size_t)(bn + srow) * K + scol;

    for (int k0 = 0; k0 < K; k0 += 32) {
        __syncthreads();
        #pragma unroll
        for (int r = 0; r < 2; ++r) {
            __builtin_amdgcn_global_load_lds(
                (const __attribute__((address_space(1))) void*)(Ag + (size_t)r * 16 * K + k0),
                (__attribute__((address_space(3))) void*)(As + w * 1024 + r * 512),
                16, 0, 0);
            __builtin_amdgcn_global_load_lds(
                (const __attribute__((address_space(1))) void*)(Bg + (size_t)r * 16 * K + k0),
                (__attribute__((address_space(3))) void*)(Bs + w * 1024 + r * 512),
                16, 0, 0);
        }
        __syncthreads();
        bf16x8 af[4], bfr[4];
        #pragma unroll
        for (int mi = 0; mi < 4; ++mi)
            af[mi] = *reinterpret_cast<const bf16x8*>(As + (wm*64 + mi*16 + lr) * 32 + lg*8);
        #pragma unroll
        for (int nj = 0; nj < 4; ++nj)
            bfr[nj] = *reinterpret_cast<const bf16x8*>(Bs + (wn*64 + nj*16 + lr) * 32 + lg*8);
        #pragma unroll
        for (int mi = 0; mi < 4; ++mi)
            #pragma unroll
            for (int nj = 0; nj < 4; ++nj)
                acc[mi][nj] = __builtin_amdgcn_mfma_f32_16x16x32_bf16(af[mi], bfr[nj], acc[mi][nj], 0, 0, 0);
    }

    float bias_v[4];
    #pragma unroll
    for (int nj = 0; nj < 4; ++nj) bias_v[nj] = bias[bn + wn*64 + nj*16 + lr];

    #pragma unroll
    for (int mi = 0; mi < 4; ++mi) {
        #pragma unroll
        for (int j = 0; j < 4; ++j) {
            size_t m = bm + wm*64 + mi*16 + lg*4 + j;
            #pragma unroll
            for (int nj = 0; nj < 4; ++nj) {
                size_t n = bn + wn*64 + nj*16 + lr;
                float v = acc[mi][nj][j] + bias_v[nj];
                if (RES) v += res[m * N + n];
                if (ACT == 1) v = 0.5f * v * (1.0f + erff(v * 0.70710678118f));
                if (OUTBF) ((short*)Cout)[m * N + n] = f2bf(v);
                else       ((float*)Cout)[m * N + n] = v;
            }
        }
    }
}

template<int ACT, bool RES, bool OUTBF>
__global__ __launch_bounds__(256)
void gemm_mfma_kernel(const short* __restrict__ A, const short* __restrict__ WT,
                      const float* __restrict__ bias, const float* __restrict__ res,
                      void* __restrict__ Cout, int M, int N, int K) {
    gemm_body<ACT, RES, OUTBF>(A, WT, bias, res, Cout, M, N, K);
}

__global__ __launch_bounds__(256)
void gemm_qkv_kernel(const short* __restrict__ A,
                     const short* __restrict__ WTq, const short* __restrict__ WTk,
                     const short* __restrict__ WTv,
                     const float* __restrict__ bq, const float* __restrict__ bk,
                     const float* __restrict__ bv,
                     short* __restrict__ Qm, short* __restrict__ Km, short* __restrict__ Vm) {
    const short* WT; const float* bias; short* C;
    if (blockIdx.z == 0)      { WT = WTq; bias = bq; C = Qm; }
    else if (blockIdx.z == 1) { WT = WTk; bias = bk; C = Km; }
    else                      { WT = WTv; bias = bv; C = Vm; }
    gemm_body<0, false, true>(A, WT, bias, nullptr, C, ROWS, D_MODEL, D_MODEL);
}

// ---------------------------------------------------------------- MFMA flash attention v6
// 1 wave per block, one (bh, 16-row q-tile) per wave. 3072 independent waves.
// No partials, no K-split, no register prefetch (fits 128 VGPR, no spill);
// latency hidden by occupancy (~3 waves/SIMD). Long q-tiles scheduled first.
__global__ __launch_bounds__(64)
void attn_mfma_kernel(const short* __restrict__ Q, const short* __restrict__ K,
                      const short* __restrict__ Vt, const short* __restrict__ qp,
                      const short* __restrict__ kp, short* __restrict__ ao) {
    int lin = blockIdx.x;                     // 0..3071
    int wid = (lin & 7) * 384 + (lin >> 3);   // bijective XCD swizzle (3072=8*384)
    int bh = wid >> 7;                        // 3 heads per XCD
    int qt = 127 - (wid & 127);               // long tasks first
    int b = bh / N_HEADS, h = bh % N_HEADS;
    __shared__ short Plds[16][72];
    int lane = threadIdx.x;
    int lr = lane & 15, lg = lane >> 4;

    const short* Kh  = K  + (size_t)(b * SEQ) * D_MODEL + h * 64;
    const short* kph = kp + (size_t)bh * SEQ * 64;
    const short* Vth = Vt + (size_t)bh * 64 * SEQ;

    int qbase = qt * 16;
    const short* Qrow  = Q  + ((size_t)(b * SEQ) + qbase + lr) * D_MODEL + h * 64;
    const short* qprow = qp + ((size_t)bh * SEQ + qbase + lr) * 64;
    bf16x8 qf0  = *reinterpret_cast<const bf16x8*>(Qrow + lg * 8);
    bf16x8 qf1  = *reinterpret_cast<const bf16x8*>(Qrow + 32 + lg * 8);
    bf16x8 qpf0 = *reinterpret_cast<const bf16x8*>(qprow + lg * 8);
    bf16x8 qpf1 = *reinterpret_cast<const bf16x8*>(qprow + 32 + lg * 8);

    f32x4 o_acc[4] = {};
    float m_run[4], l_run[4];
    #pragma unroll
    for (int r = 0; r < 4; ++r) { m_run[r] = -1e30f; l_run[r] = 0.f; }

    int nkt = qt / 4 + 1;
    int lastkt = nkt - 1;

    for (int kt = 0; kt < nkt; ++kt) {
        // V fragments (consumed in PV) — issue first so latency overlaps scores
        bf16x8 vb[4][2];
        #pragma unroll
        for (int ds = 0; ds < 4; ++ds) {
            const short* vr = Vth + (size_t)(ds * 16 + lr) * SEQ + kt * 64;
            vb[ds][0] = *reinterpret_cast<const bf16x8*>(vr + lg * 8);
            vb[ds][1] = *reinterpret_cast<const bf16x8*>(vr + 32 + lg * 8);
        }
        // K / kp fragments for this tile
        bf16x8 kf[4][2], kq[4][2];
        #pragma unroll
        for (int sub = 0; sub < 4; ++sub) {
            const short* kr  = Kh  + (size_t)(kt * 64 + sub * 16 + lr) * D_MODEL;
            const short* kpr = kph + (size_t)(kt * 64 + sub * 16 + lr) * 64;
            kf[sub][0] = *reinterpret_cast<const bf16x8*>(kr + lg * 8);
            kf[sub][1] = *reinterpret_cast<const bf16x8*>(kr + 32 + lg * 8);
            kq[sub][0] = *reinterpret_cast<const bf16x8*>(kpr + lg * 8);
            kq[sub][1] = *reinterpret_cast<const bf16x8*>(kpr + 32 + lg * 8);
        }

        f32x4 sx[4] = {}, sp[4] = {};
        __builtin_amdgcn_s_setprio(1);
        #pragma unroll
        for (int sub = 0; sub < 4; ++sub) {
            sx[sub] = __builtin_amdgcn_mfma_f32_16x16x32_bf16(qf0,  kf[sub][0], sx[sub], 0, 0, 0);
            sx[sub] = __builtin_amdgcn_mfma_f32_16x16x32_bf16(qf1,  kf[sub][1], sx[sub], 0, 0, 0);
            sp[sub] = __builtin_amdgcn_mfma_f32_16x16x32_bf16(qpf0, kq[sub][0], sp[sub], 0, 0, 0);
            sp[sub] = __builtin_amdgcn_mfma_f32_16x16x32_bf16(qpf1, kq[sub][1], sp[sub], 0, 0, 0);
        }
        __builtin_amdgcn_s_setprio(0);

        float sc[4][4];
        float pmax[4];
        bool diag = (kt == lastkt);
        #pragma unroll
        for (int r = 0; r < 4; ++r) {
            int row = qbase + lg * 4 + r;
            float mx = -1e30f;
            #pragma unroll
            for (int sub = 0; sub < 4; ++sub) {
                float v = sx[sub][r] * sp[sub][r] * (1.0f / 64.0f);
                if (diag) {
                    int col = kt * 64 + sub * 16 + lr;
                    if (col > row) v = -1e30f;
                }
                sc[sub][r] = v;
                mx = fmaxf(mx, v);
            }
            pmax[r] = mx;
        }
        #pragma unroll
        for (int off = 1; off < 16; off <<= 1)
            #pragma unroll
            for (int r = 0; r < 4; ++r)
                pmax[r] = fmaxf(pmax[r], __shfl_xor(pmax[r], off));

        float psum[4];
        #pragma unroll
        for (int r = 0; r < 4; ++r) {
            float m_new = fmaxf(m_run[r], pmax[r]);
            float scale = __expf(m_run[r] - m_new);
            m_run[r] = m_new;
            float s = 0.f;
            #pragma unroll
            for (int sub = 0; sub < 4; ++sub) {
                float p = __expf(sc[sub][r] - m_new);
                sc[sub][r] = p;
                s += p;
            }
            psum[r] = s;
            l_run[r] *= scale;
            #pragma unroll
            for (int ds = 0; ds < 4; ++ds) o_acc[ds][r] *= scale;
        }
        #pragma unroll
        for (int off = 1; off < 16; off <<= 1)
            #pragma unroll
            for (int r = 0; r < 4; ++r)
                psum[r] += __shfl_xor(psum[r], off);
        #pragma unroll
        for (int r = 0; r < 4; ++r) l_run[r] += psum[r];

        // P -> bf16 -> wave-private LDS -> A-frags (no barrier needed)
        #pragma unroll
        for (int sub = 0; sub < 4; ++sub)
            #pragma unroll
            for (int r = 0; r < 4; ++r)
                Plds[lg * 4 + r][sub * 16 + lr] = f2bf(sc[sub][r]);

        bf16x8 pa0 = *reinterpret_cast<bf16x8*>(&Plds[lr][lg * 8]);
        bf16x8 pa1 = *reinterpret_cast<bf16x8*>(&Plds[lr][32 + lg * 8]);

        __builtin_amdgcn_s_setprio(1);
        #pragma unroll
        for (int ds = 0; ds < 4; ++ds) {
            o_acc[ds] = __builtin_amdgcn_mfma_f32_16x16x32_bf16(pa0, vb[ds][0], o_acc[ds], 0, 0, 0);
            o_acc[ds] = __builtin_amdgcn_mfma_f32_16x16x32_bf16(pa1, vb[ds][1], o_acc[ds], 0, 0, 0);
        }
        __builtin_amdgcn_s_setprio(0);
    }

    #pragma unroll
    for (int ds = 0; ds < 4; ++ds)
        #pragma unroll
        for (int r = 0; r < 4; ++r) {
            int row = qbase + lg * 4 + r;
            float val = o_acc[ds][r] / l_run[r];
            ao[((size_t)(b * SEQ) + row) * D_MODEL + h * 64 + ds * 16 + lr] = f2bf(val);
        }
}

// ---------------------------------------------------------------- launch
extern "C" void kernel_launch(void* const* d_in, const int* in_sizes, int n_in,
                              void* d_out, int out_size, void* d_ws, size_t ws_size,
                              hipStream_t stream) {
    const float* x     = (const float*)d_in[0];
    const float* q_pos = (const float*)d_in[1];
    const float* k_pos = (const float*)d_in[2];
    const float* Wq = (const float*)d_in[4];
    const float* bq = (const float*)d_in[5];
    const float* Wk = (const float*)d_in[6];
    const float* bk = (const float*)d_in[7];
    const float* Wv = (const float*)d_in[8];
    const float* bv = (const float*)d_in[9];
    const float* Wo = (const float*)d_in[10];
    const float* bo = (const float*)d_in[11];
    const float* ln1_g = (const float*)d_in[12];
    const float* ln1_b = (const float*)d_in[13];
    const float* ln2_g = (const float*)d_in[14];
    const float* ln2_b = (const float*)d_in[15];
    const float* W1 = (const float*)d_in[16];
    const float* b1 = (const float*)d_in[17];
    const float* W2 = (const float*)d_in[18];
    const float* b2 = (const float*)d_in[19];
    float* out = (float*)d_out;

    char* p = (char*)d_ws;
    auto alloc = [&](size_t bytes) { char* q = p; p += (bytes + 255) & ~(size_t)255; return q; };
    const size_t SA = (size_t)ROWS * D_MODEL;
    const size_t SP = (size_t)BATCH * N_HEADS * SEQ * 64;

    short* h_bf  = (short*)alloc(SA * 2);
    short* Qm    = (short*)alloc(SA * 2);
    short* Km    = (short*)alloc(SA * 2);
    short* Vm    = (short*)alloc(SA * 2);
    short* Vt    = (short*)alloc(SP * 2);
    short* ao    = (short*)alloc(SA * 2);
    short* qp_bf = (short*)alloc(SP * 2);
    short* kp_bf = (short*)alloc(SP * 2);
    short* mid   = (short*)alloc((size_t)ROWS * D_FFN * 2);
    float* x2    = (float*)alloc(SA * 4);
    short* WTq   = (short*)alloc((size_t)D_MODEL * D_MODEL * 2);
    short* WTk   = (short*)alloc((size_t)D_MODEL * D_MODEL * 2);
    short* WTv   = (short*)alloc((size_t)D_MODEL * D_MODEL * 2);
    short* WTo   = (short*)alloc((size_t)D_MODEL * D_MODEL * 2);
    short* WT1   = (short*)alloc((size_t)D_MODEL * D_FFN * 2);
    short* WT2   = (short*)alloc((size_t)D_MODEL * D_FFN * 2);

    dim3 t768(24, 24), t1(96, 24), t2(24, 96);
    transpose_bf16_kernel<<<t768, 256, 0, stream>>>(Wq, WTq, D_MODEL, D_MODEL);
    transpose_bf16_kernel<<<t768, 256, 0, stream>>>(Wk, WTk, D_MODEL, D_MODEL);
    transpose_bf16_kernel<<<t768, 256, 0, stream>>>(Wv, WTv, D_MODEL, D_MODEL);
    transpose_bf16_kernel<<<t768, 256, 0, stream>>>(Wo, WTo, D_MODEL, D_MODEL);
    transpose_bf16_kernel<<<t1,   256, 0, stream>>>(W1, WT1, D_MODEL, D_FFN);
    transpose_bf16_kernel<<<t2,   256, 0, stream>>>(W2, WT2, D_FFN, D_MODEL);
    convert_bf16_kernel<<<SP / 2048, 256, 0, stream>>>(q_pos, qp_bf);
    convert_bf16_kernel<<<SP / 2048, 256, 0, stream>>>(k_pos, kp_bf);

    ln_kernel<<<ROWS, 256, 0, stream>>>(x, ln1_g, ln1_b, h_bf);
    gemm_qkv_kernel<<<dim3(D_MODEL/128, ROWS/128, 3), 256, 0, stream>>>(
        h_bf, WTq, WTk, WTv, bq, bk, bv, Qm, Km, Vm);
    transpose_v_kernel<<<dim3(SEQ/64, BATCH*N_HEADS), 256, 0, stream>>>(Vm, Vt);
    attn_mfma_kernel<<<3072, 64, 0, stream>>>(Qm, Km, Vt, qp_bf, kp_bf, ao);
    gemm_mfma_kernel<0, true, false><<<dim3(D_MODEL/128, ROWS/128), 256, 0, stream>>>(
        ao, WTo, bo, x, x2, ROWS, D_MODEL, D_MODEL);
    ln_kernel<<<ROWS, 256, 0, stream>>>(x2, ln2_g, ln2_b, h_bf);
    gemm_mfma_kernel<1, false, true><<<dim3(D_FFN/128, ROWS/128), 256, 0, stream>>>(
        h_bf, WT1, b1, nullptr, mid, ROWS, D_FFN, D_MODEL);
    gemm_mfma_kernel<0, true, false><<<dim3(D_MODEL/128, ROWS/128), 256, 0, stream>>>(
        mid, WT2, b2, x2, out, ROWS, D_MODEL, D_FFN);
}